// Round 7
// baseline (200.664 us; speedup 1.0000x reference)
//
#include <hip/hip_runtime.h>
#include <hip/hip_bf16.h>
#include <math.h>

// ---------------- model constants ----------------
#define T_LEN 1024
#define HID 1024
#define NHEAD 32
#define HDIM 64         // P
#define NSTATE 128      // N
#define NLVL 15
#define KCONV 4
#define INTER 2048
#define CONV_DIM 2304   // INTER + 2*N
#define PROJ 4864       // INTER + CONV_DIM + H*(NL+1)
#define EPS 1e-5f

typedef __attribute__((ext_vector_type(8))) _Float16 half8;
typedef __attribute__((ext_vector_type(4))) float float4v;
typedef unsigned short ushort_t;

__device__ __forceinline__ float softplus_f(float x) {
  return fmaxf(x, 0.f) + log1pf(expf(-fabsf(x)));
}
__device__ __forceinline__ float silu_f(float x) {
  return x / (1.f + expf(-x));
}
__device__ __forceinline__ ushort_t f2h(float f) {
  union { _Float16 h; ushort_t u; } v;
  v.h = (_Float16)f;
  return v.u;
}
__device__ __forceinline__ float h2f(ushort_t u) {
  union { ushort_t u; _Float16 h; } v;
  v.u = u;
  return (float)v.h;
}
// async global->LDS 16B: lds dst must be wave-uniform base; lane i lands at base+i*16
__device__ __forceinline__ void gload_lds16(const void* g, void* l) {
  __builtin_amdgcn_global_load_lds(
      (const __attribute__((address_space(1))) void*)g,
      (__attribute__((address_space(3))) void*)l, 16, 0, 0);
}

// ---------------- fused f32 -> f16 converts (hs, in_proj_w, out_proj_w) ----------------
#define N4_HS  (T_LEN * HID / 4)          // 262144
#define N4_WI  (PROJ * HID / 4)           // 1245184
#define N4_WO  (HID * INTER / 4)          // 524288
__global__ __launch_bounds__(256) void prep_f16(
    const float* __restrict__ hs, const float* __restrict__ wi,
    const float* __restrict__ wo, ushort_t* __restrict__ hsb,
    ushort_t* __restrict__ wib, ushort_t* __restrict__ wob) {
  int i = blockIdx.x * 256 + threadIdx.x;
  const float* src; ushort_t* dst; int j;
  if (i < N4_HS)              { src = hs; dst = hsb; j = i; }
  else if (i < N4_HS + N4_WI) { src = wi; dst = wib; j = i - N4_HS; }
  else                        { src = wo; dst = wob; j = i - N4_HS - N4_WI; }
  float4 v = reinterpret_cast<const float4*>(src)[j];
  union { ushort_t u[4]; unsigned long long ll; } o;
  o.u[0] = f2h(v.x); o.u[1] = f2h(v.y); o.u[2] = f2h(v.z); o.u[3] = f2h(v.w);
  reinterpret_cast<unsigned long long*>(dst)[j] = o.ll;
}

// ---------------- split-K f16 MFMA GEMM (dbuf + global_load_lds), f16 partials ----------------
__global__ __launch_bounds__(256) void gemm_f16_sk(
    const ushort_t* __restrict__ A, const ushort_t* __restrict__ B,
    ushort_t* __restrict__ Cpart, int M, int N, int K, int Kc) {
  __shared__ ushort_t As[2][128][32];   // 64B rows (no pad: global_load_lds layout)
  __shared__ ushort_t Bs[2][128][32];
  const int tid = threadIdx.x;
  const int w = tid >> 6, L = tid & 63;
  const int n0 = blockIdx.x * 128, m0 = blockIdx.y * 128;
  const int kbeg = blockIdx.z * Kc;
  ushort_t* __restrict__ C = Cpart + (size_t)blockIdx.z * M * N;
  const int mq = (w & 1) * 64, nq = (w >> 1) * 64;
  const int srow = (L >> 2);
  const int sch = (L & 3) * 8;

  float4v acc[4][4];
#pragma unroll
  for (int i = 0; i < 4; ++i)
#pragma unroll
    for (int j = 0; j < 4; ++j) acc[i][j] = (float4v){0.f, 0.f, 0.f, 0.f};

  const int niter = Kc / 32;
  {
    const int kk = kbeg;
#pragma unroll
    for (int j = 0; j < 2; ++j) {
      int r0 = 16 * (w * 2 + j);
      gload_lds16(A + (size_t)(m0 + r0 + srow) * K + kk + sch, &As[0][r0][0]);
      gload_lds16(B + (size_t)(n0 + r0 + srow) * K + kk + sch, &Bs[0][r0][0]);
    }
  }
  for (int it = 0; it < niter; ++it) {
    __syncthreads();
    if (it + 1 < niter) {
      const int kk = kbeg + (it + 1) * 32;
      const int nb = (it + 1) & 1;
#pragma unroll
      for (int j = 0; j < 2; ++j) {
        int r0 = 16 * (w * 2 + j);
        gload_lds16(A + (size_t)(m0 + r0 + srow) * K + kk + sch, &As[nb][r0][0]);
        gload_lds16(B + (size_t)(n0 + r0 + srow) * K + kk + sch, &Bs[nb][r0][0]);
      }
    }
    const int cb = it & 1;
    half8 af[4], bf[4];
#pragma unroll
    for (int t = 0; t < 4; ++t) {
      af[t] = *reinterpret_cast<const half8*>(&As[cb][mq + t * 16 + (L & 15)][(L >> 4) * 8]);
      bf[t] = *reinterpret_cast<const half8*>(&Bs[cb][nq + t * 16 + (L & 15)][(L >> 4) * 8]);
    }
#pragma unroll
    for (int mt = 0; mt < 4; ++mt)
#pragma unroll
      for (int nt = 0; nt < 4; ++nt)
        acc[mt][nt] = __builtin_amdgcn_mfma_f32_16x16x32_f16(af[mt], bf[nt], acc[mt][nt], 0, 0, 0);
  }
  const int qrow = (L >> 4) * 4;
#pragma unroll
  for (int mt = 0; mt < 4; ++mt) {
#pragma unroll
    for (int nt = 0; nt < 4; ++nt) {
      int col = n0 + nq + nt * 16 + (L & 15);
#pragma unroll
      for (int r = 0; r < 4; ++r) {
        int row = m0 + mq + mt * 16 + qrow + r;
        C[(size_t)row * N + col] = f2h(acc[mt][nt][r]);
      }
    }
  }
}

// ---------------- reduce 4 f16 out_proj partials + bias -> f32 out ----------------
__global__ __launch_bounds__(256) void reduce_out4(const ushort_t* __restrict__ p,
                                                   const float* __restrict__ bias,
                                                   float* __restrict__ out, int MN) {
  int i = blockIdx.x * 256 + threadIdx.x;   // half8 index
  if (i * 8 >= MN) return;
  half8 a = reinterpret_cast<const half8*>(p)[i];
  half8 b = reinterpret_cast<const half8*>(p + MN)[i];
  half8 c = reinterpret_cast<const half8*>(p + 2 * (size_t)MN)[i];
  half8 d = reinterpret_cast<const half8*>(p + 3 * (size_t)MN)[i];
  int col = (i * 8) & (HID - 1);
  float o[8];
#pragma unroll
  for (int j = 0; j < 8; ++j)
    o[j] = (float)a[j] + (float)b[j] + (float)c[j] + (float)d[j] + bias[col + j];
  float4 o0 = {o[0], o[1], o[2], o[3]}, o1 = {o[4], o[5], o[6], o[7]};
  reinterpret_cast<float4*>(out)[i * 2] = o0;
  reinterpret_cast<float4*>(out)[i * 2 + 1] = o1;
}

// ---------------- per-head: dt + fp64 scan (wave-shuffle, no barriers) ----------------
// grid = 32 heads, block = 64 lanes; lane l owns t in [l*16, l*16+16)
__global__ __launch_bounds__(64) void scan_g(
    const ushort_t* __restrict__ zh0, const ushort_t* __restrict__ zh1,
    const float* __restrict__ in_b, const float* __restrict__ dt_bias,
    const float* __restrict__ A_log, float* __restrict__ dtb,
    double* __restrict__ cgd) {
  const int h = blockIdx.x, l = threadIdx.x;
  const int c = INTER + CONV_DIM + h;
  const float bb = in_b[c] + dt_bias[h];
  const float Ae = -expf(A_log[h]);
  double pre[16];
  double acc = 0.0;
#pragma unroll
  for (int i = 0; i < 16; ++i) {
    int t = l * 16 + i;
    size_t o = (size_t)t * PROJ + c;
    float x = h2f(zh0[o]) + h2f(zh1[o]) + bb;
    float dt = softplus_f(x);
    dtb[t * NHEAD + h] = dt;
    acc += (double)(Ae * dt);
    pre[i] = acc;
  }
  double s = acc;
#pragma unroll
  for (int off = 1; off < 64; off <<= 1) {
    double o = __shfl_up(s, off, 64);
    if (l >= off) s += o;
  }
  const double base = s - acc;   // exclusive prefix of lane totals
  double* cr = cgd + (size_t)h * T_LEN + l * 16;
#pragma unroll
  for (int i = 0; i < 16; ++i) cr[i] = base + pre[i];
}

// ---------------- fused conv(K=4)+SiLU+split, with in-block V transpose ----------------
// grid (16 t-tiles, 36 c-tiles of 64). c-tile<32: v path (head = cy); else B/C.
__global__ __launch_bounds__(256) void conv_fused(
    const ushort_t* __restrict__ zh0, const ushort_t* __restrict__ zh1,
    const float* __restrict__ in_b, const float* __restrict__ conv_w,
    const float* __restrict__ dtb, const float* __restrict__ Dp,
    ushort_t* __restrict__ vt, float* __restrict__ ybuf,
    ushort_t* __restrict__ Bb, ushort_t* __restrict__ Cb) {
  __shared__ ushort_t Vl[64][68];
  __shared__ float dtl[64];
  const int tq = blockIdx.x, cy = blockIdx.y;
  const int t0 = tq * 64;
  const int tid = threadIdx.x;
  const int lane = tid & 63, g = tid >> 6;
  const bool vpath = (cy < 32);
  const int ccol = vpath ? cy * 64 + lane : INTER + (cy - 32) * 64 + lane;
  const int zcol = INTER + ccol;
  float cw[KCONV];
#pragma unroll
  for (int w = 0; w < KCONV; ++w) cw[w] = conv_w[ccol * KCONV + w];
  const float bc = in_b[zcol];
  if (vpath && tid < 64) dtl[tid] = dtb[(t0 + tid) * NHEAD + cy];
  const float Dh = vpath ? Dp[cy] : 0.f;

  float xv[19];
#pragma unroll
  for (int i = 0; i < 19; ++i) {
    int tt = t0 + g * 16 - 3 + i;
    if (tt >= 0) {
      size_t o = (size_t)tt * PROJ + zcol;
      xv[i] = h2f(zh0[o]) + h2f(zh1[o]) + bc;
    } else xv[i] = 0.f;
  }
  __syncthreads();   // dtl ready
#pragma unroll
  for (int i = 0; i < 16; ++i) {
    float acc = xv[i] * cw[0] + xv[i + 1] * cw[1] + xv[i + 2] * cw[2] + xv[i + 3] * cw[3];
    float sil = silu_f(acc);
    int tl = g * 16 + i;
    int t = t0 + tl;
    if (vpath) {
      Vl[tl][lane] = f2h(sil * dtl[tl]);                       // for transpose
      ybuf[(size_t)t * INTER + cy * 64 + lane] = sil * Dh;     // D residual
    } else if (ccol < INTER + NSTATE) {
      Bb[t * NSTATE + (ccol - INTER)] = f2h(sil);
    } else {
      Cb[t * NSTATE + (ccol - INTER - NSTATE)] = f2h(sil);
    }
  }
  if (vpath) {
    __syncthreads();
#pragma unroll
    for (int rep = 0; rep < 2; ++rep) {
      int u = tid + 256 * rep;
      int p = u >> 3, t8 = (u & 7) * 8;
      union { ushort_t u16[8]; half8 h; } o;
#pragma unroll
      for (int j = 0; j < 8; ++j) o.u16[j] = Vl[t8 + j][p];
      *reinterpret_cast<half8*>(vt + (size_t)(cy * 64 + p) * T_LEN + t0 + t8) = o.h;
    }
  }
}

// ---------------- split-K MFMA attention (level scales computed in-block) ----------------
__global__ __launch_bounds__(256) void attn_mfma(
    const ushort_t* __restrict__ Bb, const ushort_t* __restrict__ Cb,
    const ushort_t* __restrict__ vt, const double* __restrict__ cgd,
    const ushort_t* __restrict__ zh0, const ushort_t* __restrict__ zh1,
    const float* __restrict__ in_b, const float* __restrict__ L_param,
    float* __restrict__ ybuf) {
  __shared__ ushort_t Bl[64][136];
  __shared__ ushort_t Vtl[64][72];
  __shared__ ushort_t Sl[64][72];
  __shared__ float Lsl[64][16];
  __shared__ float cgq[64];
  __shared__ float cgs[64];

  const int item = blockIdx.x;
  const int h = item / 40;
  const int rem = item - h * 40;
  int qt, j;
  if (rem < 4)        { qt = rem;                 j = 0; }
  else if (rem < 12)  { qt = 4 + (rem - 4) / 2;   j = (rem - 4) % 2; }
  else if (rem < 24)  { qt = 8 + (rem - 12) / 3;  j = (rem - 12) % 3; }
  else                { qt = 12 + (rem - 24) / 4; j = (rem - 24) % 4; }

  const int tid = threadIdx.x;
  const int w = tid >> 6, L = tid & 63;
  const int tq0 = qt * 64;
  const double* cgh = cgd + (size_t)h * T_LEN;
  const double base = cgh[tq0];

  // level scales for this (head, q-tile): Ls = softplus(L_param * dl), dl from zh tail
  for (int i = tid; i < 64 * NLVL; i += 256) {
    int r = i / NLVL, l = i - r * NLVL;
    int cc = INTER + CONV_DIM + NHEAD + h * NLVL + l;
    size_t o = (size_t)(tq0 + r) * PROJ + cc;
    float x = h2f(zh0[o]) + h2f(zh1[o]) + in_b[cc];
    Lsl[r][l] = softplus_f(L_param[h * NLVL + l] * x);
  }
  if (tid < 64) cgq[tid] = (float)(cgh[tq0 + tid] - base);

  half8 cfrag[4];
  {
    const ushort_t* cr = Cb + (size_t)(tq0 + w * 16 + (L & 15)) * NSTATE + (L >> 4) * 8;
#pragma unroll
    for (int ks = 0; ks < 4; ++ks)
      cfrag[ks] = *reinterpret_cast<const half8*>(cr + ks * 32);
  }
  float4v yac[4];
#pragma unroll
  for (int i = 0; i < 4; ++i) yac[i] = (float4v){0.f, 0.f, 0.f, 0.f};

  const int qrow = w * 16 + ((L >> 4) << 2);

  const int st0 = 4 * j;
  const int st1 = min(4 * j + 4, qt + 1);
  for (int st = st0; st < st1; ++st) {
    const int ts0 = st * 64;
    __syncthreads();
#pragma unroll
    for (int i = 0; i < 4; ++i) {
      int u = tid + 256 * i;
      int row = u >> 4, kb = (u & 15) * 8;
      *reinterpret_cast<half8*>(&Bl[row][kb]) =
          *reinterpret_cast<const half8*>(Bb + (size_t)(ts0 + row) * NSTATE + kb);
    }
#pragma unroll
    for (int i = 0; i < 2; ++i) {
      int u = tid + 256 * i;
      int p = u >> 3, sc = (u & 7) * 8;
      *reinterpret_cast<half8*>(&Vtl[p][sc]) =
          *reinterpret_cast<const half8*>(vt + (size_t)(h * HDIM + p) * T_LEN + ts0 + sc);
    }
    if (tid < 64) cgs[tid] = (float)(cgh[ts0 + tid] - base);
    __syncthreads();

    float4v sac[4];
#pragma unroll
    for (int nt = 0; nt < 4; ++nt) sac[nt] = (float4v){0.f, 0.f, 0.f, 0.f};
#pragma unroll
    for (int ks = 0; ks < 4; ++ks) {
#pragma unroll
      for (int nt = 0; nt < 4; ++nt) {
        half8 bfrag = *reinterpret_cast<const half8*>(&Bl[nt * 16 + (L & 15)][ks * 32 + (L >> 4) * 8]);
        sac[nt] = __builtin_amdgcn_mfma_f32_16x16x32_f16(cfrag[ks], bfrag, sac[nt], 0, 0, 0);
      }
    }
#pragma unroll
    for (int nt = 0; nt < 4; ++nt) {
      int s = nt * 16 + (L & 15);
      int sg = ts0 + s;
      float cs = cgs[s];
#pragma unroll
      for (int r = 0; r < 4; ++r) {
        int q = qrow + r;
        int tg = tq0 + q;
        float val = 0.f;
        if (sg <= tg) {
          int lvl = 31 - __clz((unsigned)(sg ^ (tg + 1)));
          val = sac[nt][r] * __expf(cgq[q] - cs) * Lsl[q][lvl];
        }
        Sl[q][s] = f2h(val);
      }
    }
    // wait own ds_writes only (lgkmcnt(0); vmcnt=63, expcnt=7 -> no vm wait)
    __builtin_amdgcn_s_waitcnt(0xC07F);
#pragma unroll
    for (int ks = 0; ks < 2; ++ks) {
      half8 af = *reinterpret_cast<const half8*>(&Sl[w * 16 + (L & 15)][ks * 32 + (L >> 4) * 8]);
#pragma unroll
      for (int pt = 0; pt < 4; ++pt) {
        half8 bfv = *reinterpret_cast<const half8*>(&Vtl[pt * 16 + (L & 15)][ks * 32 + (L >> 4) * 8]);
        yac[pt] = __builtin_amdgcn_mfma_f32_16x16x32_f16(af, bfv, yac[pt], 0, 0, 0);
      }
    }
  }
#pragma unroll
  for (int pt = 0; pt < 4; ++pt) {
    int p = pt * 16 + (L & 15);
#pragma unroll
    for (int r = 0; r < 4; ++r) {
      int q = qrow + r;
      atomicAdd(ybuf + (size_t)(tq0 + q) * INTER + h * HDIM + p, yac[pt][r]);
    }
  }
}

// ---------------- gated RMSNorm -> f16 ----------------
__global__ __launch_bounds__(256) void rmsnorm_gate(
    const float* __restrict__ ybuf, const ushort_t* __restrict__ zh0,
    const ushort_t* __restrict__ zh1, const float* __restrict__ in_b,
    const float* __restrict__ w, ushort_t* __restrict__ yhf) {
  __shared__ float red[4];
  const int t = blockIdx.x, tid = threadIdx.x;
  const size_t ro = (size_t)t * PROJ;
  const float* yrow = ybuf + (size_t)t * INTER;
  float yg[8];
  float ss = 0.f;
#pragma unroll
  for (int i = 0; i < 8; ++i) {
    int c = tid + 256 * i;
    float z = h2f(zh0[ro + c]) + h2f(zh1[ro + c]) + in_b[c];
    float g = yrow[c] * silu_f(z);
    yg[i] = g;
    ss += g * g;
  }
#pragma unroll
  for (int off = 32; off; off >>= 1) ss += __shfl_down(ss, off, 64);
  if ((tid & 63) == 0) red[tid >> 6] = ss;
  __syncthreads();
  if (tid == 0) red[0] = red[0] + red[1] + red[2] + red[3];
  __syncthreads();
  const float scale = rsqrtf(red[0] / (float)INTER + EPS);
#pragma unroll
  for (int i = 0; i < 8; ++i) {
    int c = tid + 256 * i;
    yhf[(size_t)t * INTER + c] = f2h(yg[i] * scale * w[c]);
  }
}

// ---------------- launch ----------------
extern "C" void kernel_launch(void* const* d_in, const int* in_sizes, int n_in,
                              void* d_out, int out_size, void* d_ws, size_t ws_size,
                              hipStream_t stream) {
  const float* hs        = (const float*)d_in[0];
  const float* in_proj_w = (const float*)d_in[1];
  const float* in_proj_b = (const float*)d_in[2];
  const float* conv_w    = (const float*)d_in[3];
  const float* dt_bias   = (const float*)d_in[4];
  const float* A_log     = (const float*)d_in[5];
  const float* L_param   = (const float*)d_in[6];
  const float* Dp        = (const float*)d_in[7];
  const float* rms_w     = (const float*)d_in[8];
  const float* out_proj_w= (const float*)d_in[9];
  const float* out_proj_b= (const float*)d_in[10];
  float* out = (float*)d_out;

  char* W = (char*)d_ws;
  size_t off = 0;
  auto alloc = [&](size_t bytes) { void* p = W + off; off = (off + bytes + 255) & ~(size_t)255; return p; };
  double*   cgd = (double*)  alloc((size_t)NHEAD * T_LEN * 8);
  ushort_t* zh  = (ushort_t*)alloc((size_t)2 * T_LEN * PROJ * 2);   // in_proj f16 partials
  ushort_t* opp = (ushort_t*)alloc((size_t)4 * T_LEN * HID * 2);    // out_proj f16 partials
  float*    ybuf= (float*)   alloc((size_t)T_LEN * INTER * 4);
  float*    dtb = (float*)   alloc((size_t)T_LEN * NHEAD * 4);
  ushort_t* hsb = (ushort_t*)alloc((size_t)T_LEN * HID * 2);
  ushort_t* Wib = (ushort_t*)alloc((size_t)PROJ * HID * 2);
  ushort_t* Wob = (ushort_t*)alloc((size_t)HID * INTER * 2);
  ushort_t* yhf = (ushort_t*)alloc((size_t)T_LEN * INTER * 2);
  ushort_t* vt  = (ushort_t*)alloc((size_t)T_LEN * INTER * 2);
  ushort_t* Bb  = (ushort_t*)alloc((size_t)T_LEN * NSTATE * 2);
  ushort_t* Cb  = (ushort_t*)alloc((size_t)T_LEN * NSTATE * 2);
  ushort_t* zh0 = zh;
  ushort_t* zh1 = zh + (size_t)T_LEN * PROJ;

  // 1. fused f32->f16 conversions
  prep_f16<<<(N4_HS + N4_WI + N4_WO) / 256, 256, 0, stream>>>(
      hs, in_proj_w, out_proj_w, hsb, Wib, Wob);

  // 2. in_proj split-K=2 -> f16 partials (bias folded in consumers)
  gemm_f16_sk<<<dim3(PROJ / 128, T_LEN / 128, 2), 256, 0, stream>>>(
      hsb, Wib, zh, T_LEN, PROJ, HID, HID / 2);

  // 3. dt + fp64 wave-shuffle scan
  scan_g<<<NHEAD, 64, 0, stream>>>(zh0, zh1, in_proj_b, dt_bias, A_log, dtb, cgd);

  // 4. fused conv + silu + split + V transpose
  conv_fused<<<dim3(T_LEN / 64, 36), 256, 0, stream>>>(
      zh0, zh1, in_proj_b, conv_w, dtb, Dp, vt, ybuf, Bb, Cb);

  // 5. split-K MFMA attention (computes level scales in-block)
  attn_mfma<<<NHEAD * 40, 256, 0, stream>>>(Bb, Cb, vt, cgd, zh0, zh1, in_proj_b,
                                            L_param, ybuf);

  // 6. gated RMSNorm -> f16
  rmsnorm_gate<<<T_LEN, 256, 0, stream>>>(ybuf, zh0, zh1, in_proj_b, rms_w, yhf);

  // 7. out_proj split-K=4 -> f16 partials, then reduce(+bias)
  gemm_f16_sk<<<dim3(HID / 128, T_LEN / 128, 4), 256, 0, stream>>>(
      yhf, Wob, opp, T_LEN, HID, INTER, INTER / 4);
  reduce_out4<<<(T_LEN * HID / 8 + 255) / 256, 256, 0, stream>>>(
      opp, out_proj_b, out, T_LEN * HID);
}